// Round 14
// baseline (425.482 us; speedup 1.0000x reference)
//
#include <hip/hip_runtime.h>
#include <hip/hip_bf16.h>
#include <cstdint>
#include <cstddef>

#define B 8
#define C 192
#define H 128
#define W 128
#define HW (H * W)
#define CHW ((size_t)C * HW)
#define K C                    // GEMM K dim = 192

typedef __attribute__((ext_vector_type(8))) short short8v;
typedef __attribute__((ext_vector_type(4))) float f32x4;
typedef __attribute__((ext_vector_type(4))) unsigned short ushort4v;

__device__ __forceinline__ float bf2f(unsigned short s) {
    union { float f; unsigned u; } cv; cv.u = ((unsigned)s) << 16; return cv.f;
}
__device__ __forceinline__ unsigned short f2bf(float f) {
    union { __hip_bfloat16 h; unsigned short u; } cv;
    cv.h = __float2bfloat16(f);                  // native v_cvt on gfx950
    return cv.u;
}

// ---------------- weight prepack fp32 -> bf16 (par | loc | out) ----------------
__global__ void prepack_kernel(const float* __restrict__ pw, const float* __restrict__ lw,
                               const float* __restrict__ ow, unsigned short* __restrict__ wb) {
    int i = blockIdx.x * 256 + threadIdx.x;
    const int NPW = 3 * C * K, NL = C * K;
    if (i < NPW) wb[i] = f2bf(pw[i]);
    else if (i < NPW + NL) wb[i] = f2bf(lw[i - NPW]);
    else if (i < NPW + 2 * NL) wb[i] = f2bf(ow[i - NPW - NL]);
}

// -------- FUSED LayerNorm + gates conv, single-pass x, shfl stats --------
// Block = 128 pixels, 256 threads (4 waves x 32 px).
__global__ __launch_bounds__(256, 4)
void lngates_kernel(const float* __restrict__ x, const float* __restrict__ lw,
                    const float* __restrict__ lb, const unsigned short* __restrict__ wb,
                    const float* __restrict__ bias, unsigned short* __restrict__ ZT,
                    unsigned short* __restrict__ PA, unsigned short* __restrict__ PU,
                    unsigned short* __restrict__ PG) {
    __shared__ char smem[96 * 384];              // weight half tile
    __shared__ float lwb[2][192];
    int tid = threadIdx.x;
    int p0 = blockIdx.x * 128;
    int bl = p0 >> 14;

    if (tid < 192) { lwb[0][tid] = lw[tid]; lwb[1][tid] = lb[tid]; }

    int lane = tid & 63, wv = tid >> 6;
    int pw0 = p0 + wv * 32;                      // wave's 32 pixels
    int lr = lane & 15, lh = lane >> 4;
    int sw = (lr & 7) << 4;

    // ---- load x once into bf16 frags + per-lane partial stats ----
    short8v bfr[2][6];
    float sum0 = 0.f, sq0 = 0.f, sum1 = 0.f, sq1 = 0.f;
#pragma unroll
    for (int s = 0; s < 2; ++s) {
        int px = pw0 + s * 16 + lr;
        const float* xp = x + (size_t)bl * CHW + (px & 16383);
#pragma unroll
        for (int t = 0; t < 6; ++t) {
            short8v v;
#pragma unroll
            for (int j = 0; j < 8; ++j) {
                float xv = xp[(size_t)(t * 32 + lh * 8 + j) * HW];
                if (s == 0) { sum0 += xv; sq0 += xv * xv; }
                else        { sum1 += xv; sq1 += xv * xv; }
                v[j] = (short)f2bf(xv);
            }
            bfr[s][t] = v;
        }
    }
    // ---- reduce across the 4 lanes (lh=0..3) sharing each pixel ----
#pragma unroll
    for (int mask = 16; mask <= 32; mask <<= 1) {
        sum0 += __shfl_xor(sum0, mask, 64); sq0 += __shfl_xor(sq0, mask, 64);
        sum1 += __shfl_xor(sum1, mask, 64); sq1 += __shfl_xor(sq1, mask, 64);
    }
    float mean0 = sum0 * (1.0f / C);
    float rs0 = rsqrtf(fmaxf(sq0 * (1.0f / C) - mean0 * mean0, 0.f) + 1e-6f);
    float mean1 = sum1 * (1.0f / C);
    float rs1 = rsqrtf(fmaxf(sq1 * (1.0f / C) - mean1 * mean1, 0.f) + 1e-6f);

    __syncthreads();                             // lwb ready

    // ---- normalize in-register, write ZT ----
#pragma unroll
    for (int s = 0; s < 2; ++s) {
        int px = pw0 + s * 16 + lr;
        float mean = s ? mean1 : mean0, rs = s ? rs1 : rs0;
#pragma unroll
        for (int t = 0; t < 6; ++t) {
            short8v v = bfr[s][t];
#pragma unroll
            for (int j = 0; j < 8; ++j) {
                int c = t * 32 + lh * 8 + j;
                float r = (bf2f((unsigned short)v[j]) - mean) * rs * lwb[0][c] + lwb[1][c];
                v[j] = (short)f2bf(r);
            }
            bfr[s][t] = v;
            *(short8v*)(ZT + (size_t)px * K + t * 32 + lh * 8) = v;
        }
    }

    // ---- gates GEMM: 3 gate types x 2 half weight tiles ----
    for (int gy = 0; gy < 3; ++gy) {
        for (int hf = 0; hf < 2; ++hf) {
            __syncthreads();                     // also orders ZT stores (first iter)
            const unsigned short* wsrc = wb + (size_t)gy * C * K + (size_t)hf * 96 * K;
#pragma unroll
            for (int it = 0; it < 9; ++it) {
                int e8 = it * 256 + tid;
                int row = e8 / 24;
                int cb = (e8 % 24) * 16;
                short8v v = *(const short8v*)(wsrc + e8 * 8);
                *(short8v*)(smem + row * 384 + (cb ^ ((row & 7) << 4))) = v;
            }
            __syncthreads();

            for (int otl = 0; otl < 6; ++otl) {
                int ot = hf * 6 + otl;
                int rb = (otl * 16 + lr) * 384;
                int o = ot * 16 + lr;
                f32x4 acc[2];
#pragma unroll
                for (int s = 0; s < 2; ++s) acc[s] = (f32x4){0.f, 0.f, 0.f, 0.f};
#pragma unroll
                for (int t = 0; t < 6; ++t) {
                    short8v af = *(const short8v*)(smem + rb + ((t * 64 + lh * 16) ^ sw));
#pragma unroll
                    for (int s = 0; s < 2; ++s)
                        acc[s] = __builtin_amdgcn_mfma_f32_16x16x32_bf16(bfr[s][t], af, acc[s], 0, 0, 0);
                }
                float bi = bias[gy * C + o];
#pragma unroll
                for (int s = 0; s < 2; ++s) {
                    int pst = pw0 + s * 16 + lh * 4;
                    int hw = pst & 16383;
                    ushort4v q;
#pragma unroll
                    for (int j = 0; j < 4; ++j) {
                        float v = acc[s][j] + bi;
                        v = 1.f / (1.f + __expf(-v));
                        if (gy == 1) v *= bf2f(ZT[(size_t)(pst + j) * K + o]);
                        q[j] = f2bf(v);
                    }
                    unsigned short* dst = (gy == 0) ? PA : ((gy == 1) ? PU : PG);
                    *(ushort4v*)(dst + (size_t)bl * CHW + (size_t)o * HW + hw) = q;
                }
            }
        }
    }
}

// ---------------- MFMA 1x1 conv, half-tile LDS weights, D[p][o] orientation -----
// MODE 1: +bias -> PA (bf16 NCHW)
// MODE 2: input = yin bf16 NCHW; +bias +xres -> Pf (fp32 NCHW)
template <int MODE>
__global__ __launch_bounds__(256, 4)
void conv_mfma_kernel(const unsigned short* __restrict__ zt, const unsigned short* __restrict__ yin,
                      const unsigned short* __restrict__ wb, const float* __restrict__ bias,
                      const float* __restrict__ xres, float* __restrict__ Pf,
                      unsigned short* __restrict__ PA) {
    __shared__ char smem[96 * 384];              // 36864 B half weight tile
    int tid = threadIdx.x;
    int lane = tid & 63, wv = tid >> 6;
    int p0 = blockIdx.x * 128 + wv * 32;         // wave's 32 pixels
    int lr = lane & 15, lh = lane >> 4;
    int sw = (lr & 7) << 4;

    short8v bfr[2][6];
    if (MODE != 2) {
#pragma unroll
        for (int s = 0; s < 2; ++s) {
            const unsigned short* zr = zt + (size_t)(p0 + s * 16 + lr) * K + lh * 8;
#pragma unroll
            for (int t = 0; t < 6; ++t) bfr[s][t] = *(const short8v*)(zr + t * 32);
        }
    } else {
        int bl = p0 >> 14, hwb = p0 & 16383;
        const unsigned short* yb = yin + (size_t)bl * CHW;
#pragma unroll
        for (int s = 0; s < 2; ++s) {
            int hw = hwb + s * 16 + lr;
#pragma unroll
            for (int t = 0; t < 6; ++t) {
                int c0 = t * 32 + lh * 8;
                short8v v;
#pragma unroll
                for (int j = 0; j < 8; ++j)
                    v[j] = (short)yb[(size_t)(c0 + j) * HW + hw];
                bfr[s][t] = v;
            }
        }
    }

    for (int hf = 0; hf < 2; ++hf) {
        __syncthreads();
        const unsigned short* wsrc = wb + (size_t)hf * 96 * K;
#pragma unroll
        for (int it = 0; it < 9; ++it) {
            int e8 = it * 256 + tid;
            int row = e8 / 24;
            int cb = (e8 % 24) * 16;
            short8v v = *(const short8v*)(wsrc + e8 * 8);
            *(short8v*)(smem + row * 384 + (cb ^ ((row & 7) << 4))) = v;
        }
        __syncthreads();

        for (int otl = 0; otl < 6; ++otl) {
            int ot = hf * 6 + otl;
            int rb = (otl * 16 + lr) * 384;
            int o = ot * 16 + lr;
            f32x4 acc[2];
#pragma unroll
            for (int s = 0; s < 2; ++s) acc[s] = (f32x4){0.f, 0.f, 0.f, 0.f};
#pragma unroll
            for (int t = 0; t < 6; ++t) {
                short8v af = *(const short8v*)(smem + rb + ((t * 64 + lh * 16) ^ sw));
#pragma unroll
                for (int s = 0; s < 2; ++s)
                    acc[s] = __builtin_amdgcn_mfma_f32_16x16x32_bf16(bfr[s][t], af, acc[s], 0, 0, 0);
            }
            float bi = bias[o];
#pragma unroll
            for (int s = 0; s < 2; ++s) {
                int pst = p0 + s * 16 + lh * 4;
                int bl = pst >> 14, hw = pst & 16383;
                if (MODE == 1) {
                    ushort4v q;
#pragma unroll
                    for (int j = 0; j < 4; ++j) q[j] = f2bf(acc[s][j] + bi);
                    *(ushort4v*)(PA + (size_t)bl * CHW + (size_t)o * HW + hw) = q;
                } else {
                    size_t ad = (size_t)bl * CHW + (size_t)o * HW + hw;
                    f32x4 x4 = *(const f32x4*)(xres + ad);
                    f32x4 q;
#pragma unroll
                    for (int j = 0; j < 4; ++j) q[j] = acc[s][j] + bi + x4[j];
                    *(f32x4*)(Pf + ad) = q;
                }
            }
        }
    }
}

// ------- 3x3 depthwise conv, LDS-tiled: block = 8h x 16w pixels, all 192 ch -------
#define TROWS 180              // 10*18 staged pixel rows
#define LPAD  392              // padded LDS row stride in bytes
__global__ __launch_bounds__(256, 2)
void dw3x3_kernel(const unsigned short* __restrict__ zt, const float* __restrict__ wgt,
                  unsigned short* __restrict__ dt) {
    __shared__ char lds[TROWS * LPAD];           // 70560 B
    int tid = threadIdx.x;
    int bx = blockIdx.x;
    int bimg = bx >> 7;
    int rem = bx & 127;
    int th = rem >> 3, tw = rem & 7;
    int h0 = th * 8, w0 = tw * 16;
    size_t ibase = (size_t)bimg * HW;

    for (int e = tid; e < TROWS * 24; e += 256) {
        int row = e / 24, ch = e % 24;
        int hh = row / 18, ww = row % 18;
        int h = h0 - 1 + hh, w = w0 - 1 + ww;
        short8v v;
        if (h >= 0 && h < H && w >= 0 && w < W)
            v = *(const short8v*)(zt + (ibase + h * W + w) * K + ch * 8);
        else
            v = (short8v){0, 0, 0, 0, 0, 0, 0, 0};
        *(short8v*)(lds + row * LPAD + ch * 16) = v;
    }
    __syncthreads();

    int w_l = tid & 15, h_l = (tid >> 4) & 7, half = tid >> 7;
    int p_out = (h0 + h_l) * W + (w0 + w_l);
    unsigned short* dp = dt + (ibase + p_out) * K + half * 96;
#pragma unroll
    for (int cc = 0; cc < 12; ++cc) {
        int c8 = half * 12 + cc;
        float acc[8];
#pragma unroll
        for (int j = 0; j < 8; ++j) acc[j] = 0.f;
#pragma unroll
        for (int dy = -1; dy <= 1; ++dy) {
#pragma unroll
            for (int dx = -1; dx <= 1; ++dx) {
                int row = (h_l + 1 + dy) * 18 + (w_l + 1 + dx);
                short8v zv = *(const short8v*)(lds + row * LPAD + c8 * 16);
                int t = (dy + 1) * 3 + (dx + 1);
#pragma unroll
                for (int j = 0; j < 8; ++j)
                    acc[j] += wgt[(c8 * 8 + j) * 9 + t] * bf2f((unsigned short)zv[j]);
            }
        }
        short8v ov;
#pragma unroll
        for (int j = 0; j < 8; ++j) ov[j] = (short)f2bf(acc[j]);
        *(short8v*)(dp + cc * 8) = ov;
    }
}

// ------ fused scans, shuffle-free chunked both axes; A/U staged in LDS ------
__global__ __launch_bounds__(1024)
void scan_fused_kernel(const unsigned short* __restrict__ A_, const unsigned short* __restrict__ U_,
                       const unsigned short* __restrict__ G_, unsigned short* __restrict__ LY) {
    extern __shared__ float SMEM[];
    float* Sl = SMEM;                            // [HW]
    unsigned* AU = (unsigned*)(SMEM + HW);       // [HW]
    float* CA = SMEM + 2 * HW;                   // [8*132] fwd A
    float* CU = CA + 1056;                       // [8*132] fwd U -> exclusive prefix
    float* DA = CU + 1056;                       // [8*132] bwd A
    float* DU = DA + 1056;                       // [8*132] bwd U -> exclusive prefix
    int tid = threadIdx.x;
    size_t pb = (size_t)blockIdx.x * HW;

    int h = tid >> 3, wc = tid & 7;
    int swzA = (h & 7) << 2;
    unsigned au[16];
    {
        const unsigned short* ap = A_ + pb + h * W + wc * 16;
        const unsigned short* up = U_ + pb + h * W + wc * 16;
        short8v a0 = *(const short8v*)ap, a1 = *(const short8v*)(ap + 8);
        short8v u0 = *(const short8v*)up, u1 = *(const short8v*)(up + 8);
#pragma unroll
        for (int i = 0; i < 8; ++i) {
            au[i]     = (unsigned)(unsigned short)a0[i] | ((unsigned)(unsigned short)u0[i] << 16);
            au[8 + i] = (unsigned)(unsigned short)a1[i] | ((unsigned)(unsigned short)u1[i] << 16);
        }
    }
#pragma unroll
    for (int i = 0; i < 16; ++i)
        AU[h * 128 + ((wc * 16 + i) ^ swzA)] = au[i];
    {
        float Af = 1.f, Uf = 0.f, Ab = 1.f, Ub = 0.f;
#pragma unroll
        for (int i = 0; i < 16; ++i) {
            float a = bf2f(au[i] & 0xffff), u = bf2f(au[i] >> 16);
            Uf = a * Uf + u; Af *= a;
        }
#pragma unroll
        for (int i = 15; i >= 0; --i) {
            float a = bf2f(au[i] & 0xffff), u = bf2f(au[i] >> 16);
            Ub = a * Ub + u; Ab *= a;
        }
        CA[wc * 132 + h] = Af; CU[wc * 132 + h] = Uf;
        DA[wc * 132 + h] = Ab; DU[wc * 132 + h] = Ub;
    }
    __syncthreads();

    if (tid < 128) {
        float s = 0.f;
#pragma unroll
        for (int k = 0; k < 8; ++k) {
            float Aa = CA[k * 132 + tid], Uu = CU[k * 132 + tid];
            CU[k * 132 + tid] = s;
            s = Aa * s + Uu;
        }
    } else if (tid < 256) {
        int hh = tid - 128;
        float s = 0.f;
#pragma unroll
        for (int k = 7; k >= 0; --k) {
            float Aa = DA[k * 132 + hh], Uu = DU[k * 132 + hh];
            DU[k * 132 + hh] = s;
            s = Aa * s + Uu;
        }
    }
    __syncthreads();

    {
        float sf = CU[wc * 132 + h];
        float sfa[16];
#pragma unroll
        for (int i = 0; i < 16; ++i) {
            float a = bf2f(au[i] & 0xffff), u = bf2f(au[i] >> 16);
            sf = a * sf + u; sfa[i] = sf;
        }
        float sb = DU[wc * 132 + h];
#pragma unroll
        for (int i = 15; i >= 0; --i) {
            float a = bf2f(au[i] & 0xffff), u = bf2f(au[i] >> 16);
            sb = a * sb + u;
            Sl[h * W + ((wc * 16 + i) ^ swzA)] = sfa[i] + sb;
        }
    }
    __syncthreads();

    int w = tid & 127, hc = tid >> 7;
    int h0 = hc * 16;
    unsigned au2[16];
#pragma unroll
    for (int i = 0; i < 16; ++i) {
        int hh = h0 + i;
        au2[i] = AU[hh * 128 + (w ^ ((hh & 7) << 2))];
    }
    {
        float Af = 1.f, Uf = 0.f, Ab = 1.f, Ub = 0.f;
#pragma unroll
        for (int i = 0; i < 16; ++i) {
            float a = bf2f(au2[i] & 0xffff), u = bf2f(au2[i] >> 16);
            Uf = a * Uf + u; Af *= a;
        }
#pragma unroll
        for (int i = 15; i >= 0; --i) {
            float a = bf2f(au2[i] & 0xffff), u = bf2f(au2[i] >> 16);
            Ub = a * Ub + u; Ab *= a;
        }
        CA[hc * 132 + w] = Af; CU[hc * 132 + w] = Uf;
        DA[hc * 132 + w] = Ab; DU[hc * 132 + w] = Ub;
    }
    __syncthreads();

    if (tid < 128) {
        float s = 0.f;
#pragma unroll
        for (int k = 0; k < 8; ++k) {
            float Aa = CA[k * 132 + tid], Uu = CU[k * 132 + tid];
            CU[k * 132 + tid] = s;
            s = Aa * s + Uu;
        }
    } else if (tid < 256) {
        int ww = tid - 128;
        float s = 0.f;
#pragma unroll
        for (int k = 7; k >= 0; --k) {
            float Aa = DA[k * 132 + ww], Uu = DU[k * 132 + ww];
            DU[k * 132 + ww] = s;
            s = Aa * s + Uu;
        }
    }
    __syncthreads();

    {
        float sf = CU[hc * 132 + w];
        float sfa[16];
#pragma unroll
        for (int i = 0; i < 16; ++i) {
            float a = bf2f(au2[i] & 0xffff), u = bf2f(au2[i] >> 16);
            sf = a * sf + u; sfa[i] = sf;
        }
        float sb = DU[hc * 132 + w];
#pragma unroll
        for (int i = 15; i >= 0; --i) {
            float a = bf2f(au2[i] & 0xffff), u = bf2f(au2[i] >> 16);
            sb = a * sb + u;
            int hh = h0 + i;
            size_t off = pb + (size_t)hh * W + w;
            float g = bf2f(G_[off]);
            float wsum = Sl[hh * W + (w ^ ((hh & 7) << 2))];
            float v = bf2f(LY[off]) + 0.5f * g * (wsum + sfa[i] + sb);
            LY[off] = f2bf(v / (1.f + __expf(-v)));
        }
    }
}

extern "C" void kernel_launch(void* const* d_in, const int* in_sizes, int n_in,
                              void* d_out, int out_size, void* d_ws, size_t ws_size,
                              hipStream_t stream) {
    const float* x     = (const float*)d_in[0];
    const float* ln_w  = (const float*)d_in[1];
    const float* ln_b  = (const float*)d_in[2];
    const float* dw_w  = (const float*)d_in[3];
    const float* loc_w = (const float*)d_in[4];
    const float* loc_b = (const float*)d_in[5];
    const float* par_w = (const float*)d_in[6];
    const float* par_b = (const float*)d_in[7];
    const float* out_w = (const float*)d_in[8];
    const float* out_b = (const float*)d_in[9];
    float* out = (float*)d_out;
    unsigned short* wsu = (unsigned short*)d_ws;

    // ws (bf16 units): WB(184320) | A | U | G | ZT(->LOC->Y) | DT, each nb*CHW
    const int WBN = 5 * C * K;                 // 184320
    int nb = 8;
    while (nb > 1) {
        size_t need = (size_t)WBN * 2 + (size_t)5 * nb * CHW * 2;
        if (need <= ws_size) break;
        nb >>= 1;
    }

    prepack_kernel<<<(WBN + 255) / 256, 256, 0, stream>>>(par_w, loc_w, out_w, wsu);

    const size_t SCAN_LDS = (size_t)(2 * HW + 4 * 1056) * 4;   // 147,968 B

    for (int b0 = 0; b0 < B; b0 += nb) {
        size_t ge = (size_t)nb * CHW;
        unsigned short* WB = wsu;
        unsigned short* Ab = wsu + WBN;
        unsigned short* Ub = Ab + ge;
        unsigned short* Gb = Ub + ge;
        unsigned short* ZT = Gb + ge;          // z [p][K]; later LOC (bf16 NCHW), then Y
        unsigned short* DT = ZT + ge;
        const float* xg = x + (size_t)b0 * CHW;
        int npg = nb * HW;

        // 1. fused LayerNorm + gates -> ZT, A, U, G
        lngates_kernel<<<npg / 128, 256, 0, stream>>>(
            xg, ln_w, ln_b, WB, par_b, ZT, Ab, Ub, Gb);
        // 2. depthwise 3x3 -> DT [p][K]  (LDS-tiled)
        dw3x3_kernel<<<nb * 128, 256, 0, stream>>>(ZT, dw_w, DT);
        // 3. local conv -> LOC (bf16 NCHW) overwriting ZT (now dead)
        conv_mfma_kernel<1><<<npg / 128, 256, 0, stream>>>(
            DT, nullptr, WB + 3 * C * K, loc_b, nullptr, nullptr, ZT);
        // 4. fused scans + loc add + silu, in place -> Y (= ZT buffer)
        scan_fused_kernel<<<nb * C, 1024, SCAN_LDS, stream>>>(Ab, Ub, Gb, ZT);
        // 5. out conv (reads Y bf16) + bias + residual -> d_out
        conv_mfma_kernel<2><<<npg / 128, 256, 0, stream>>>(
            nullptr, ZT, WB + 4 * C * K, out_b, xg, out + (size_t)b0 * CHW, nullptr);
    }
}

// Round 15
// 403.180 us; speedup vs baseline: 1.0553x; 1.0553x over previous
//
#include <hip/hip_runtime.h>
#include <cstdint>
#include <cstddef>

#define B 8
#define C 192
#define H 128
#define W 128
#define HW (H * W)
#define CHW ((size_t)C * HW)
#define K C                    // GEMM K dim = 192

typedef __attribute__((ext_vector_type(8))) short short8v;
typedef __attribute__((ext_vector_type(4))) float f32x4;
typedef __attribute__((ext_vector_type(4))) unsigned short ushort4v;

__device__ __forceinline__ float bf2f(unsigned short s) {
    union { float f; unsigned u; } cv; cv.u = ((unsigned)s) << 16; return cv.f;
}
__device__ __forceinline__ unsigned short f2bf(float f) {
    union { float f; unsigned u; } cv; cv.f = f;
    unsigned r = (cv.u + 0x7fffu + ((cv.u >> 16) & 1u)) >> 16;
    return (unsigned short)r;
}

// ---------------- weight prepack fp32 -> bf16 (par | loc | out) ----------------
__global__ void prepack_kernel(const float* __restrict__ pw, const float* __restrict__ lw,
                               const float* __restrict__ ow, unsigned short* __restrict__ wb) {
    int i = blockIdx.x * 256 + threadIdx.x;
    const int NPW = 3 * C * K, NL = C * K;
    if (i < NPW) wb[i] = f2bf(pw[i]);
    else if (i < NPW + NL) wb[i] = f2bf(lw[i - NPW]);
    else if (i < NPW + 2 * NL) wb[i] = f2bf(ow[i - NPW - NL]);
}

// -------- FUSED LayerNorm + gates conv (3 gy) -> ZT [p][K], A,U,G bf16 NCHW --------
// Block = 128 pixels, 256 threads. 48-row weight tiles (small LDS -> 6 blocks/CU).
__global__ __launch_bounds__(256, 6)
void lngates_kernel(const float* __restrict__ x, const float* __restrict__ lw,
                    const float* __restrict__ lb, const unsigned short* __restrict__ wb,
                    const float* __restrict__ bias, unsigned short* __restrict__ ZT,
                    unsigned short* __restrict__ PA, unsigned short* __restrict__ PU,
                    unsigned short* __restrict__ PG) {
    __shared__ char smem[48 * 384];              // 18432 B quarter weight tile
    __shared__ float stat[2][128];               // mean, rs per pixel
    __shared__ float lwb[2][192];
    int tid = threadIdx.x;
    int p0 = blockIdx.x * 128;
    int bl = p0 >> 14, hwb = p0 & 16383;

    if (tid < 192) { lwb[0][tid] = lw[tid]; lwb[1][tid] = lb[tid]; }

    // ---- phase L1: per-pixel channel stats (2 threads/pixel) ----
    {
        float* part = (float*)smem;              // [2][2][128] = 2 KB
        int px = tid & 127, half = tid >> 7;
        const float* xp = x + (size_t)bl * CHW + hwb + px;
        float sum = 0.f, sq = 0.f;
        for (int c = half * 96; c < half * 96 + 96; ++c) {
            float v = xp[(size_t)c * HW];
            sum += v; sq += v * v;
        }
        part[half * 128 + px] = sum;
        part[256 + half * 128 + px] = sq;
        __syncthreads();
        if (tid < 128) {
            float s = part[tid] + part[128 + tid];
            float q = part[256 + tid] + part[384 + tid];
            float mean = s * (1.0f / C);
            float var = fmaxf(q * (1.0f / C) - mean * mean, 0.f);
            stat[0][tid] = mean;
            stat[1][tid] = rsqrtf(var + 1e-6f);
        }
        __syncthreads();
    }

    int lane = tid & 63, wv = tid >> 6;
    int pw0 = p0 + wv * 32;                      // wave's 32 pixels
    int lr = lane & 15, lh = lane >> 4;
    int sw = (lr & 7) << 4;

    // ---- phase L2: build z B-frags from x (normalize in regs), write ZT ----
    short8v bfr[2][6];
#pragma unroll
    for (int s = 0; s < 2; ++s) {
        int px = pw0 + s * 16 + lr;
        int hw = px & 16383;
        float mean = stat[0][px - p0], rs = stat[1][px - p0];
        const float* xp = x + (size_t)bl * CHW + hw;
#pragma unroll
        for (int t = 0; t < 6; ++t) {
            short8v v;
#pragma unroll
            for (int j = 0; j < 8; ++j) {
                int c = t * 32 + lh * 8 + j;
                float r = (xp[(size_t)c * HW] - mean) * rs * lwb[0][c] + lwb[1][c];
                v[j] = (short)f2bf(r);
            }
            bfr[s][t] = v;
            *(short8v*)(ZT + (size_t)px * K + t * 32 + lh * 8) = v;
        }
    }

    // ---- gates GEMM: 3 gate types x 4 quarter weight tiles (48 rows each) ----
    for (int gy = 0; gy < 3; ++gy) {
        for (int hf = 0; hf < 4; ++hf) {
            __syncthreads();                     // prior compute done before restage
            const unsigned short* wsrc = wb + (size_t)gy * C * K + (size_t)hf * 48 * K;
#pragma unroll
            for (int it = 0; it < 5; ++it) {
                int e8 = it * 256 + tid;         // 1152 chunks of 8 elems
                if (e8 < 1152) {
                    int row = e8 / 24;
                    int cb = (e8 % 24) * 16;
                    short8v v = *(const short8v*)(wsrc + e8 * 8);
                    *(short8v*)(smem + row * 384 + (cb ^ ((row & 7) << 4))) = v;
                }
            }
            __syncthreads();

            for (int otl = 0; otl < 3; ++otl) {
                int ot = hf * 3 + otl;
                int rb = (otl * 16 + lr) * 384;
                int o = ot * 16 + lr;            // output channel (within gy)
                f32x4 acc[2];
#pragma unroll
                for (int s = 0; s < 2; ++s) acc[s] = (f32x4){0.f, 0.f, 0.f, 0.f};
#pragma unroll
                for (int t = 0; t < 6; ++t) {
                    short8v af = *(const short8v*)(smem + rb + ((t * 64 + lh * 16) ^ sw));
#pragma unroll
                    for (int s = 0; s < 2; ++s)
                        acc[s] = __builtin_amdgcn_mfma_f32_16x16x32_bf16(bfr[s][t], af, acc[s], 0, 0, 0);
                }
                float bi = bias[gy * C + o];
#pragma unroll
                for (int s = 0; s < 2; ++s) {
                    int pst = pw0 + s * 16 + lh * 4;
                    int hw = pst & 16383;
                    ushort4v q;
#pragma unroll
                    for (int j = 0; j < 4; ++j) {
                        float v = acc[s][j] + bi;
                        v = 1.f / (1.f + __expf(-v));
                        if (gy == 1) v *= bf2f(ZT[(size_t)(pst + j) * K + o]);  // L2-hot own tile
                        q[j] = f2bf(v);
                    }
                    unsigned short* dst = (gy == 0) ? PA : ((gy == 1) ? PU : PG);
                    *(ushort4v*)(dst + (size_t)bl * CHW + (size_t)o * HW + hw) = q;
                }
            }
        }
    }
}

// ---------------- MFMA 1x1 conv, half-tile LDS weights, D[p][o] orientation -----
// MODE 1: +bias -> PA (bf16 NCHW)
// MODE 2: input = yin bf16 NCHW; +bias +xres -> Pf (fp32 NCHW)
template <int MODE>
__global__ __launch_bounds__(256, 4)
void conv_mfma_kernel(const unsigned short* __restrict__ zt, const unsigned short* __restrict__ yin,
                      const unsigned short* __restrict__ wb, const float* __restrict__ bias,
                      const float* __restrict__ xres, float* __restrict__ Pf,
                      unsigned short* __restrict__ PA) {
    __shared__ char smem[96 * 384];              // 36864 B half weight tile
    int tid = threadIdx.x;
    int lane = tid & 63, wv = tid >> 6;
    int p0 = blockIdx.x * 128 + wv * 32;         // wave's 32 pixels
    int lr = lane & 15, lh = lane >> 4;
    int sw = (lr & 7) << 4;

    short8v bfr[2][6];
    if (MODE != 2) {
#pragma unroll
        for (int s = 0; s < 2; ++s) {
            const unsigned short* zr = zt + (size_t)(p0 + s * 16 + lr) * K + lh * 8;
#pragma unroll
            for (int t = 0; t < 6; ++t) bfr[s][t] = *(const short8v*)(zr + t * 32);
        }
    } else {
        int bl = p0 >> 14, hwb = p0 & 16383;
        const unsigned short* yb = yin + (size_t)bl * CHW;
#pragma unroll
        for (int s = 0; s < 2; ++s) {
            int hw = hwb + s * 16 + lr;
#pragma unroll
            for (int t = 0; t < 6; ++t) {
                int c0 = t * 32 + lh * 8;
                short8v v;
#pragma unroll
                for (int j = 0; j < 8; ++j)
                    v[j] = (short)yb[(size_t)(c0 + j) * HW + hw];
                bfr[s][t] = v;
            }
        }
    }

    for (int hf = 0; hf < 2; ++hf) {
        __syncthreads();
        const unsigned short* wsrc = wb + (size_t)hf * 96 * K;
#pragma unroll
        for (int it = 0; it < 9; ++it) {
            int e8 = it * 256 + tid;
            int row = e8 / 24;
            int cb = (e8 % 24) * 16;
            short8v v = *(const short8v*)(wsrc + e8 * 8);
            *(short8v*)(smem + row * 384 + (cb ^ ((row & 7) << 4))) = v;
        }
        __syncthreads();

        for (int otl = 0; otl < 6; ++otl) {
            int ot = hf * 6 + otl;
            int rb = (otl * 16 + lr) * 384;
            int o = ot * 16 + lr;
            f32x4 acc[2];
#pragma unroll
            for (int s = 0; s < 2; ++s) acc[s] = (f32x4){0.f, 0.f, 0.f, 0.f};
#pragma unroll
            for (int t = 0; t < 6; ++t) {
                short8v af = *(const short8v*)(smem + rb + ((t * 64 + lh * 16) ^ sw));
#pragma unroll
                for (int s = 0; s < 2; ++s)
                    acc[s] = __builtin_amdgcn_mfma_f32_16x16x32_bf16(bfr[s][t], af, acc[s], 0, 0, 0);
            }
            float bi = bias[o];
#pragma unroll
            for (int s = 0; s < 2; ++s) {
                int pst = p0 + s * 16 + lh * 4;
                int bl = pst >> 14, hw = pst & 16383;
                if (MODE == 1) {
                    ushort4v q;
#pragma unroll
                    for (int j = 0; j < 4; ++j) q[j] = f2bf(acc[s][j] + bi);
                    *(ushort4v*)(PA + (size_t)bl * CHW + (size_t)o * HW + hw) = q;
                } else {
                    size_t ad = (size_t)bl * CHW + (size_t)o * HW + hw;
                    f32x4 x4 = *(const f32x4*)(xres + ad);
                    f32x4 q;
#pragma unroll
                    for (int j = 0; j < 4; ++j) q[j] = acc[s][j] + bi + x4[j];
                    *(f32x4*)(Pf + ad) = q;
                }
            }
        }
    }
}

// ------- 3x3 depthwise conv, LDS-tiled: block = 8h x 16w pixels, all 192 ch -------
#define TROWS 180              // 10*18 staged pixel rows
#define LPAD  392              // padded LDS row stride in bytes
__global__ __launch_bounds__(256, 2)
void dw3x3_kernel(const unsigned short* __restrict__ zt, const float* __restrict__ wgt,
                  unsigned short* __restrict__ dt) {
    __shared__ char lds[TROWS * LPAD];           // 70560 B
    int tid = threadIdx.x;
    int bx = blockIdx.x;
    int bimg = bx >> 7;
    int rem = bx & 127;
    int th = rem >> 3, tw = rem & 7;
    int h0 = th * 8, w0 = tw * 16;
    size_t ibase = (size_t)bimg * HW;

    for (int e = tid; e < TROWS * 24; e += 256) {
        int row = e / 24, ch = e % 24;
        int hh = row / 18, ww = row % 18;
        int h = h0 - 1 + hh, w = w0 - 1 + ww;
        short8v v;
        if (h >= 0 && h < H && w >= 0 && w < W)
            v = *(const short8v*)(zt + (ibase + h * W + w) * K + ch * 8);
        else
            v = (short8v){0, 0, 0, 0, 0, 0, 0, 0};
        *(short8v*)(lds + row * LPAD + ch * 16) = v;
    }
    __syncthreads();

    int w_l = tid & 15, h_l = (tid >> 4) & 7, half = tid >> 7;
    int p_out = (h0 + h_l) * W + (w0 + w_l);
    unsigned short* dp = dt + (ibase + p_out) * K + half * 96;
#pragma unroll
    for (int cc = 0; cc < 12; ++cc) {
        int c8 = half * 12 + cc;
        float acc[8];
#pragma unroll
        for (int j = 0; j < 8; ++j) acc[j] = 0.f;
#pragma unroll
        for (int dy = -1; dy <= 1; ++dy) {
#pragma unroll
            for (int dx = -1; dx <= 1; ++dx) {
                int row = (h_l + 1 + dy) * 18 + (w_l + 1 + dx);
                short8v zv = *(const short8v*)(lds + row * LPAD + c8 * 16);
                int t = (dy + 1) * 3 + (dx + 1);
#pragma unroll
                for (int j = 0; j < 8; ++j)
                    acc[j] += wgt[(c8 * 8 + j) * 9 + t] * bf2f((unsigned short)zv[j]);
            }
        }
        short8v ov;
#pragma unroll
        for (int j = 0; j < 8; ++j) ov[j] = (short)f2bf(acc[j]);
        *(short8v*)(dp + cc * 8) = ov;
    }
}

// ------ fused scans, shuffle-free chunked both axes; A/U staged in LDS ------
__global__ __launch_bounds__(1024)
void scan_fused_kernel(const unsigned short* __restrict__ A_, const unsigned short* __restrict__ U_,
                       const unsigned short* __restrict__ G_, unsigned short* __restrict__ LY) {
    extern __shared__ float SMEM[];
    float* Sl = SMEM;                            // [HW]
    unsigned* AU = (unsigned*)(SMEM + HW);       // [HW]
    float* CA = SMEM + 2 * HW;                   // [8*132] fwd A
    float* CU = CA + 1056;                       // [8*132] fwd U -> exclusive prefix
    float* DA = CU + 1056;                       // [8*132] bwd A
    float* DU = DA + 1056;                       // [8*132] bwd U -> exclusive prefix
    int tid = threadIdx.x;
    size_t pb = (size_t)blockIdx.x * HW;

    int h = tid >> 3, wc = tid & 7;
    int swzA = (h & 7) << 2;
    unsigned au[16];
    {
        const unsigned short* ap = A_ + pb + h * W + wc * 16;
        const unsigned short* up = U_ + pb + h * W + wc * 16;
        short8v a0 = *(const short8v*)ap, a1 = *(const short8v*)(ap + 8);
        short8v u0 = *(const short8v*)up, u1 = *(const short8v*)(up + 8);
#pragma unroll
        for (int i = 0; i < 8; ++i) {
            au[i]     = (unsigned)(unsigned short)a0[i] | ((unsigned)(unsigned short)u0[i] << 16);
            au[8 + i] = (unsigned)(unsigned short)a1[i] | ((unsigned)(unsigned short)u1[i] << 16);
        }
    }
#pragma unroll
    for (int i = 0; i < 16; ++i)
        AU[h * 128 + ((wc * 16 + i) ^ swzA)] = au[i];
    {
        float Af = 1.f, Uf = 0.f, Ab = 1.f, Ub = 0.f;
#pragma unroll
        for (int i = 0; i < 16; ++i) {
            float a = bf2f(au[i] & 0xffff), u = bf2f(au[i] >> 16);
            Uf = a * Uf + u; Af *= a;
        }
#pragma unroll
        for (int i = 15; i >= 0; --i) {
            float a = bf2f(au[i] & 0xffff), u = bf2f(au[i] >> 16);
            Ub = a * Ub + u; Ab *= a;
        }
        CA[wc * 132 + h] = Af; CU[wc * 132 + h] = Uf;
        DA[wc * 132 + h] = Ab; DU[wc * 132 + h] = Ub;
    }
    __syncthreads();

    if (tid < 128) {
        float s = 0.f;
#pragma unroll
        for (int k = 0; k < 8; ++k) {
            float Aa = CA[k * 132 + tid], Uu = CU[k * 132 + tid];
            CU[k * 132 + tid] = s;
            s = Aa * s + Uu;
        }
    } else if (tid < 256) {
        int hh = tid - 128;
        float s = 0.f;
#pragma unroll
        for (int k = 7; k >= 0; --k) {
            float Aa = DA[k * 132 + hh], Uu = DU[k * 132 + hh];
            DU[k * 132 + hh] = s;
            s = Aa * s + Uu;
        }
    }
    __syncthreads();

    {
        float sf = CU[wc * 132 + h];
        float sfa[16];
#pragma unroll
        for (int i = 0; i < 16; ++i) {
            float a = bf2f(au[i] & 0xffff), u = bf2f(au[i] >> 16);
            sf = a * sf + u; sfa[i] = sf;
        }
        float sb = DU[wc * 132 + h];
#pragma unroll
        for (int i = 15; i >= 0; --i) {
            float a = bf2f(au[i] & 0xffff), u = bf2f(au[i] >> 16);
            sb = a * sb + u;
            Sl[h * W + ((wc * 16 + i) ^ swzA)] = sfa[i] + sb;
        }
    }
    __syncthreads();

    int w = tid & 127, hc = tid >> 7;
    int h0 = hc * 16;
    unsigned au2[16];
#pragma unroll
    for (int i = 0; i < 16; ++i) {
        int hh = h0 + i;
        au2[i] = AU[hh * 128 + (w ^ ((hh & 7) << 2))];
    }
    {
        float Af = 1.f, Uf = 0.f, Ab = 1.f, Ub = 0.f;
#pragma unroll
        for (int i = 0; i < 16; ++i) {
            float a = bf2f(au2[i] & 0xffff), u = bf2f(au2[i] >> 16);
            Uf = a * Uf + u; Af *= a;
        }
#pragma unroll
        for (int i = 15; i >= 0; --i) {
            float a = bf2f(au2[i] & 0xffff), u = bf2f(au2[i] >> 16);
            Ub = a * Ub + u; Ab *= a;
        }
        CA[hc * 132 + w] = Af; CU[hc * 132 + w] = Uf;
        DA[hc * 132 + w] = Ab; DU[hc * 132 + w] = Ub;
    }
    __syncthreads();

    if (tid < 128) {
        float s = 0.f;
#pragma unroll
        for (int k = 0; k < 8; ++k) {
            float Aa = CA[k * 132 + tid], Uu = CU[k * 132 + tid];
            CU[k * 132 + tid] = s;
            s = Aa * s + Uu;
        }
    } else if (tid < 256) {
        int ww = tid - 128;
        float s = 0.f;
#pragma unroll
        for (int k = 7; k >= 0; --k) {
            float Aa = DA[k * 132 + ww], Uu = DU[k * 132 + ww];
            DU[k * 132 + ww] = s;
            s = Aa * s + Uu;
        }
    }
    __syncthreads();

    {
        float sf = CU[hc * 132 + w];
        float sfa[16];
#pragma unroll
        for (int i = 0; i < 16; ++i) {
            float a = bf2f(au2[i] & 0xffff), u = bf2f(au2[i] >> 16);
            sf = a * sf + u; sfa[i] = sf;
        }
        float sb = DU[hc * 132 + w];
#pragma unroll
        for (int i = 15; i >= 0; --i) {
            float a = bf2f(au2[i] & 0xffff), u = bf2f(au2[i] >> 16);
            sb = a * sb + u;
            int hh = h0 + i;
            size_t off = pb + (size_t)hh * W + w;
            float g = bf2f(G_[off]);
            float wsum = Sl[hh * W + (w ^ ((hh & 7) << 2))];
            float v = bf2f(LY[off]) + 0.5f * g * (wsum + sfa[i] + sb);
            LY[off] = f2bf(v / (1.f + __expf(-v)));
        }
    }
}

extern "C" void kernel_launch(void* const* d_in, const int* in_sizes, int n_in,
                              void* d_out, int out_size, void* d_ws, size_t ws_size,
                              hipStream_t stream) {
    const float* x     = (const float*)d_in[0];
    const float* ln_w  = (const float*)d_in[1];
    const float* ln_b  = (const float*)d_in[2];
    const float* dw_w  = (const float*)d_in[3];
    const float* loc_w = (const float*)d_in[4];
    const float* loc_b = (const float*)d_in[5];
    const float* par_w = (const float*)d_in[6];
    const float* par_b = (const float*)d_in[7];
    const float* out_w = (const float*)d_in[8];
    const float* out_b = (const float*)d_in[9];
    float* out = (float*)d_out;
    unsigned short* wsu = (unsigned short*)d_ws;

    // ws (bf16 units): WB(184320) | A | U | G | ZT(->LOC->Y) | DT, each nb*CHW
    const int WBN = 5 * C * K;                 // 184320
    int nb = 8;
    while (nb > 1) {
        size_t need = (size_t)WBN * 2 + (size_t)5 * nb * CHW * 2;
        if (need <= ws_size) break;
        nb >>= 1;
    }

    prepack_kernel<<<(WBN + 255) / 256, 256, 0, stream>>>(par_w, loc_w, out_w, wsu);

    const size_t SCAN_LDS = (size_t)(2 * HW + 4 * 1056) * 4;   // 147,968 B

    for (int b0 = 0; b0 < B; b0 += nb) {
        size_t ge = (size_t)nb * CHW;
        unsigned short* WB = wsu;
        unsigned short* Ab = wsu + WBN;
        unsigned short* Ub = Ab + ge;
        unsigned short* Gb = Ub + ge;
        unsigned short* ZT = Gb + ge;          // z [p][K]; later LOC (bf16 NCHW), then Y
        unsigned short* DT = ZT + ge;
        const float* xg = x + (size_t)b0 * CHW;
        int npg = nb * HW;

        // 1. fused LayerNorm + gates -> ZT, A, U, G
        lngates_kernel<<<npg / 128, 256, 0, stream>>>(
            xg, ln_w, ln_b, WB, par_b, ZT, Ab, Ub, Gb);
        // 2. depthwise 3x3 -> DT [p][K]  (LDS-tiled)
        dw3x3_kernel<<<nb * 128, 256, 0, stream>>>(ZT, dw_w, DT);
        // 3. local conv -> LOC (bf16 NCHW) overwriting ZT (now dead)
        conv_mfma_kernel<1><<<npg / 128, 256, 0, stream>>>(
            DT, nullptr, WB + 3 * C * K, loc_b, nullptr, nullptr, ZT);
        // 4. fused scans + loc add + silu, in place -> Y (= ZT buffer)
        scan_fused_kernel<<<nb * C, 1024, SCAN_LDS, stream>>>(Ab, Ub, Gb, ZT);
        // 5. out conv (reads Y bf16) + bias + residual -> d_out
        conv_mfma_kernel<2><<<npg / 128, 256, 0, stream>>>(
            nullptr, ZT, WB + 4 * C * K, out_b, xg, out + (size_t)b0 * CHW, nullptr);
    }
}

// Round 16
// 320.192 us; speedup vs baseline: 1.3288x; 1.2592x over previous
//
#include <hip/hip_runtime.h>
#include <cstdint>
#include <cstddef>

#define B 8
#define C 192
#define H 128
#define W 128
#define HW (H * W)
#define CHW ((size_t)C * HW)
#define K C                    // GEMM K dim = 192

typedef __attribute__((ext_vector_type(8))) short short8v;
typedef __attribute__((ext_vector_type(4))) float f32x4;
typedef __attribute__((ext_vector_type(4))) unsigned short ushort4v;

__device__ __forceinline__ float bf2f(unsigned short s) {
    union { float f; unsigned u; } cv; cv.u = ((unsigned)s) << 16; return cv.f;
}
__device__ __forceinline__ unsigned short f2bf(float f) {
    union { float f; unsigned u; } cv; cv.f = f;
    unsigned r = (cv.u + 0x7fffu + ((cv.u >> 16) & 1u)) >> 16;
    return (unsigned short)r;
}

// ---------------- weight prepack fp32 -> bf16 (par | loc | out) ----------------
__global__ void prepack_kernel(const float* __restrict__ pw, const float* __restrict__ lw,
                               const float* __restrict__ ow, unsigned short* __restrict__ wb) {
    int i = blockIdx.x * 256 + threadIdx.x;
    const int NPW = 3 * C * K, NL = C * K;
    if (i < NPW) wb[i] = f2bf(pw[i]);
    else if (i < NPW + NL) wb[i] = f2bf(lw[i - NPW]);
    else if (i < NPW + 2 * NL) wb[i] = f2bf(ow[i - NPW - NL]);
}

// -------- FUSED LayerNorm + gates conv (3 gy) -> ZT [p][K], A,U,G bf16 NCHW --------
// Block = 256 pixels, 512 threads (8 waves). 96-row weight tiles, VGPR cap 128.
__global__ __launch_bounds__(512, 4)
void lngates_kernel(const float* __restrict__ x, const float* __restrict__ lw,
                    const float* __restrict__ lb, const unsigned short* __restrict__ wb,
                    const float* __restrict__ bias, unsigned short* __restrict__ ZT,
                    unsigned short* __restrict__ PA, unsigned short* __restrict__ PU,
                    unsigned short* __restrict__ PG) {
    __shared__ char smem[96 * 384];              // 36864 B half weight tile
    __shared__ float stat[2][256];               // mean, rs per pixel
    __shared__ float lwb[2][192];
    int tid = threadIdx.x;
    int p0 = blockIdx.x * 256;
    int bl = p0 >> 14, hwb = p0 & 16383;

    if (tid < 192) { lwb[0][tid] = lw[tid]; lwb[1][tid] = lb[tid]; }

    // ---- phase L1: per-pixel channel stats (2 threads/pixel) ----
    {
        float* part = (float*)smem;              // [2][2][256] = 4 KB
        int px = tid & 255, half = tid >> 8;
        const float* xp = x + (size_t)bl * CHW + hwb + px;
        float sum = 0.f, sq = 0.f;
        for (int c = half * 96; c < half * 96 + 96; ++c) {
            float v = xp[(size_t)c * HW];
            sum += v; sq += v * v;
        }
        part[half * 256 + px] = sum;
        part[512 + half * 256 + px] = sq;
        __syncthreads();
        if (tid < 256) {
            float s = part[tid] + part[256 + tid];
            float q = part[512 + tid] + part[768 + tid];
            float mean = s * (1.0f / C);
            float var = fmaxf(q * (1.0f / C) - mean * mean, 0.f);
            stat[0][tid] = mean;
            stat[1][tid] = rsqrtf(var + 1e-6f);
        }
        __syncthreads();
    }

    int lane = tid & 63, wv = tid >> 6;          // wv 0..7
    int pw0 = p0 + wv * 32;                      // wave's 32 pixels
    int lr = lane & 15, lh = lane >> 4;
    int sw = (lr & 7) << 4;

    // ---- phase L2: build z B-frags from x (normalize in regs), write ZT ----
    short8v bfr[2][6];
#pragma unroll
    for (int s = 0; s < 2; ++s) {
        int px = pw0 + s * 16 + lr;
        int hw = px & 16383;
        float mean = stat[0][px - p0], rs = stat[1][px - p0];
        const float* xp = x + (size_t)bl * CHW + hw;
#pragma unroll
        for (int t = 0; t < 6; ++t) {
            short8v v;
#pragma unroll
            for (int j = 0; j < 8; ++j) {
                int c = t * 32 + lh * 8 + j;
                float r = (xp[(size_t)c * HW] - mean) * rs * lwb[0][c] + lwb[1][c];
                v[j] = (short)f2bf(r);
            }
            bfr[s][t] = v;
            *(short8v*)(ZT + (size_t)px * K + t * 32 + lh * 8) = v;
        }
    }

    // ---- gates GEMM: 3 gate types x 2 half weight tiles (96 rows each) ----
    for (int gy = 0; gy < 3; ++gy) {
        for (int hf = 0; hf < 2; ++hf) {
            __syncthreads();                     // prior compute done before restage
            const unsigned short* wsrc = wb + (size_t)gy * C * K + (size_t)hf * 96 * K;
#pragma unroll
            for (int it = 0; it < 5; ++it) {
                int e8 = it * 512 + tid;         // 2304 chunks of 8 elems
                if (e8 < 2304) {
                    int row = e8 / 24;
                    int cb = (e8 % 24) * 16;
                    short8v v = *(const short8v*)(wsrc + e8 * 8);
                    *(short8v*)(smem + row * 384 + (cb ^ ((row & 7) << 4))) = v;
                }
            }
            __syncthreads();

            for (int otl = 0; otl < 6; ++otl) {
                int ot = hf * 6 + otl;
                int rb = (otl * 16 + lr) * 384;
                int o = ot * 16 + lr;            // output channel (within gy)
                f32x4 acc[2];
#pragma unroll
                for (int s = 0; s < 2; ++s) acc[s] = (f32x4){0.f, 0.f, 0.f, 0.f};
#pragma unroll
                for (int t = 0; t < 6; ++t) {
                    short8v af = *(const short8v*)(smem + rb + ((t * 64 + lh * 16) ^ sw));
#pragma unroll
                    for (int s = 0; s < 2; ++s)
                        acc[s] = __builtin_amdgcn_mfma_f32_16x16x32_bf16(bfr[s][t], af, acc[s], 0, 0, 0);
                }
                float bi = bias[gy * C + o];
#pragma unroll
                for (int s = 0; s < 2; ++s) {
                    int pst = pw0 + s * 16 + lh * 4;
                    int hw = pst & 16383;
                    ushort4v q;
#pragma unroll
                    for (int j = 0; j < 4; ++j) {
                        float v = acc[s][j] + bi;
                        v = 1.f / (1.f + __expf(-v));
                        if (gy == 1) v *= bf2f(ZT[(size_t)(pst + j) * K + o]);  // L2-hot own tile
                        q[j] = f2bf(v);
                    }
                    unsigned short* dst = (gy == 0) ? PA : ((gy == 1) ? PU : PG);
                    *(ushort4v*)(dst + (size_t)bl * CHW + (size_t)o * HW + hw) = q;
                }
            }
        }
    }
}

// ---------------- MFMA 1x1 conv, half-tile LDS weights, D[p][o] orientation -----
// MODE 1: +bias -> PA (bf16 NCHW)
// MODE 2: input = yin bf16 NCHW; +bias +xres -> Pf (fp32 NCHW)
template <int MODE>
__global__ __launch_bounds__(256, 4)
void conv_mfma_kernel(const unsigned short* __restrict__ zt, const unsigned short* __restrict__ yin,
                      const unsigned short* __restrict__ wb, const float* __restrict__ bias,
                      const float* __restrict__ xres, float* __restrict__ Pf,
                      unsigned short* __restrict__ PA) {
    __shared__ char smem[96 * 384];              // 36864 B half weight tile
    int tid = threadIdx.x;
    int lane = tid & 63, wv = tid >> 6;
    int p0 = blockIdx.x * 128 + wv * 32;         // wave's 32 pixels
    int lr = lane & 15, lh = lane >> 4;
    int sw = (lr & 7) << 4;

    short8v bfr[2][6];
    if (MODE != 2) {
#pragma unroll
        for (int s = 0; s < 2; ++s) {
            const unsigned short* zr = zt + (size_t)(p0 + s * 16 + lr) * K + lh * 8;
#pragma unroll
            for (int t = 0; t < 6; ++t) bfr[s][t] = *(const short8v*)(zr + t * 32);
        }
    } else {
        int bl = p0 >> 14, hwb = p0 & 16383;
        const unsigned short* yb = yin + (size_t)bl * CHW;
#pragma unroll
        for (int s = 0; s < 2; ++s) {
            int hw = hwb + s * 16 + lr;
#pragma unroll
            for (int t = 0; t < 6; ++t) {
                int c0 = t * 32 + lh * 8;
                short8v v;
#pragma unroll
                for (int j = 0; j < 8; ++j)
                    v[j] = (short)yb[(size_t)(c0 + j) * HW + hw];
                bfr[s][t] = v;
            }
        }
    }

    for (int hf = 0; hf < 2; ++hf) {
        __syncthreads();
        const unsigned short* wsrc = wb + (size_t)hf * 96 * K;
#pragma unroll
        for (int it = 0; it < 9; ++it) {
            int e8 = it * 256 + tid;
            int row = e8 / 24;
            int cb = (e8 % 24) * 16;
            short8v v = *(const short8v*)(wsrc + e8 * 8);
            *(short8v*)(smem + row * 384 + (cb ^ ((row & 7) << 4))) = v;
        }
        __syncthreads();

        for (int otl = 0; otl < 6; ++otl) {
            int ot = hf * 6 + otl;
            int rb = (otl * 16 + lr) * 384;
            int o = ot * 16 + lr;
            f32x4 acc[2];
#pragma unroll
            for (int s = 0; s < 2; ++s) acc[s] = (f32x4){0.f, 0.f, 0.f, 0.f};
#pragma unroll
            for (int t = 0; t < 6; ++t) {
                short8v af = *(const short8v*)(smem + rb + ((t * 64 + lh * 16) ^ sw));
#pragma unroll
                for (int s = 0; s < 2; ++s)
                    acc[s] = __builtin_amdgcn_mfma_f32_16x16x32_bf16(bfr[s][t], af, acc[s], 0, 0, 0);
            }
            float bi = bias[o];
#pragma unroll
            for (int s = 0; s < 2; ++s) {
                int pst = p0 + s * 16 + lh * 4;
                int bl = pst >> 14, hw = pst & 16383;
                if (MODE == 1) {
                    ushort4v q;
#pragma unroll
                    for (int j = 0; j < 4; ++j) q[j] = f2bf(acc[s][j] + bi);
                    *(ushort4v*)(PA + (size_t)bl * CHW + (size_t)o * HW + hw) = q;
                } else {
                    size_t ad = (size_t)bl * CHW + (size_t)o * HW + hw;
                    f32x4 x4 = *(const f32x4*)(xres + ad);
                    f32x4 q;
#pragma unroll
                    for (int j = 0; j < 4; ++j) q[j] = acc[s][j] + bi + x4[j];
                    *(f32x4*)(Pf + ad) = q;
                }
            }
        }
    }
}

// ------- 3x3 depthwise conv, LDS-tiled: block = 8h x 16w pixels, all 192 ch -------
#define TROWS 180              // 10*18 staged pixel rows
#define LPAD  392              // padded LDS row stride in bytes
__global__ __launch_bounds__(256, 2)
void dw3x3_kernel(const unsigned short* __restrict__ zt, const float* __restrict__ wgt,
                  unsigned short* __restrict__ dt) {
    __shared__ char lds[TROWS * LPAD];           // 70560 B
    int tid = threadIdx.x;
    int bx = blockIdx.x;
    int bimg = bx >> 7;
    int rem = bx & 127;
    int th = rem >> 3, tw = rem & 7;
    int h0 = th * 8, w0 = tw * 16;
    size_t ibase = (size_t)bimg * HW;

    for (int e = tid; e < TROWS * 24; e += 256) {
        int row = e / 24, ch = e % 24;
        int hh = row / 18, ww = row % 18;
        int h = h0 - 1 + hh, w = w0 - 1 + ww;
        short8v v;
        if (h >= 0 && h < H && w >= 0 && w < W)
            v = *(const short8v*)(zt + (ibase + h * W + w) * K + ch * 8);
        else
            v = (short8v){0, 0, 0, 0, 0, 0, 0, 0};
        *(short8v*)(lds + row * LPAD + ch * 16) = v;
    }
    __syncthreads();

    int w_l = tid & 15, h_l = (tid >> 4) & 7, half = tid >> 7;
    int p_out = (h0 + h_l) * W + (w0 + w_l);
    unsigned short* dp = dt + (ibase + p_out) * K + half * 96;
#pragma unroll
    for (int cc = 0; cc < 12; ++cc) {
        int c8 = half * 12 + cc;
        float acc[8];
#pragma unroll
        for (int j = 0; j < 8; ++j) acc[j] = 0.f;
#pragma unroll
        for (int dy = -1; dy <= 1; ++dy) {
#pragma unroll
            for (int dx = -1; dx <= 1; ++dx) {
                int row = (h_l + 1 + dy) * 18 + (w_l + 1 + dx);
                short8v zv = *(const short8v*)(lds + row * LPAD + c8 * 16);
                int t = (dy + 1) * 3 + (dx + 1);
#pragma unroll
                for (int j = 0; j < 8; ++j)
                    acc[j] += wgt[(c8 * 8 + j) * 9 + t] * bf2f((unsigned short)zv[j]);
            }
        }
        short8v ov;
#pragma unroll
        for (int j = 0; j < 8; ++j) ov[j] = (short)f2bf(acc[j]);
        *(short8v*)(dp + cc * 8) = ov;
    }
}

// ------ fused scans, shuffle-free chunked both axes; A/U staged in LDS ------
__global__ __launch_bounds__(1024)
void scan_fused_kernel(const unsigned short* __restrict__ A_, const unsigned short* __restrict__ U_,
                       const unsigned short* __restrict__ G_, unsigned short* __restrict__ LY) {
    extern __shared__ float SMEM[];
    float* Sl = SMEM;                            // [HW]
    unsigned* AU = (unsigned*)(SMEM + HW);       // [HW]
    float* CA = SMEM + 2 * HW;                   // [8*132] fwd A
    float* CU = CA + 1056;                       // [8*132] fwd U -> exclusive prefix
    float* DA = CU + 1056;                       // [8*132] bwd A
    float* DU = DA + 1056;                       // [8*132] bwd U -> exclusive prefix
    int tid = threadIdx.x;
    size_t pb = (size_t)blockIdx.x * HW;

    int h = tid >> 3, wc = tid & 7;
    int swzA = (h & 7) << 2;
    unsigned au[16];
    {
        const unsigned short* ap = A_ + pb + h * W + wc * 16;
        const unsigned short* up = U_ + pb + h * W + wc * 16;
        short8v a0 = *(const short8v*)ap, a1 = *(const short8v*)(ap + 8);
        short8v u0 = *(const short8v*)up, u1 = *(const short8v*)(up + 8);
#pragma unroll
        for (int i = 0; i < 8; ++i) {
            au[i]     = (unsigned)(unsigned short)a0[i] | ((unsigned)(unsigned short)u0[i] << 16);
            au[8 + i] = (unsigned)(unsigned short)a1[i] | ((unsigned)(unsigned short)u1[i] << 16);
        }
    }
#pragma unroll
    for (int i = 0; i < 16; ++i)
        AU[h * 128 + ((wc * 16 + i) ^ swzA)] = au[i];
    {
        float Af = 1.f, Uf = 0.f, Ab = 1.f, Ub = 0.f;
#pragma unroll
        for (int i = 0; i < 16; ++i) {
            float a = bf2f(au[i] & 0xffff), u = bf2f(au[i] >> 16);
            Uf = a * Uf + u; Af *= a;
        }
#pragma unroll
        for (int i = 15; i >= 0; --i) {
            float a = bf2f(au[i] & 0xffff), u = bf2f(au[i] >> 16);
            Ub = a * Ub + u; Ab *= a;
        }
        CA[wc * 132 + h] = Af; CU[wc * 132 + h] = Uf;
        DA[wc * 132 + h] = Ab; DU[wc * 132 + h] = Ub;
    }
    __syncthreads();

    if (tid < 128) {
        float s = 0.f;
#pragma unroll
        for (int k = 0; k < 8; ++k) {
            float Aa = CA[k * 132 + tid], Uu = CU[k * 132 + tid];
            CU[k * 132 + tid] = s;
            s = Aa * s + Uu;
        }
    } else if (tid < 256) {
        int hh = tid - 128;
        float s = 0.f;
#pragma unroll
        for (int k = 7; k >= 0; --k) {
            float Aa = DA[k * 132 + hh], Uu = DU[k * 132 + hh];
            DU[k * 132 + hh] = s;
            s = Aa * s + Uu;
        }
    }
    __syncthreads();

    {
        float sf = CU[wc * 132 + h];
        float sfa[16];
#pragma unroll
        for (int i = 0; i < 16; ++i) {
            float a = bf2f(au[i] & 0xffff), u = bf2f(au[i] >> 16);
            sf = a * sf + u; sfa[i] = sf;
        }
        float sb = DU[wc * 132 + h];
#pragma unroll
        for (int i = 15; i >= 0; --i) {
            float a = bf2f(au[i] & 0xffff), u = bf2f(au[i] >> 16);
            sb = a * sb + u;
            Sl[h * W + ((wc * 16 + i) ^ swzA)] = sfa[i] + sb;
        }
    }
    __syncthreads();

    int w = tid & 127, hc = tid >> 7;
    int h0 = hc * 16;
    unsigned au2[16];
#pragma unroll
    for (int i = 0; i < 16; ++i) {
        int hh = h0 + i;
        au2[i] = AU[hh * 128 + (w ^ ((hh & 7) << 2))];
    }
    {
        float Af = 1.f, Uf = 0.f, Ab = 1.f, Ub = 0.f;
#pragma unroll
        for (int i = 0; i < 16; ++i) {
            float a = bf2f(au2[i] & 0xffff), u = bf2f(au2[i] >> 16);
            Uf = a * Uf + u; Af *= a;
        }
#pragma unroll
        for (int i = 15; i >= 0; --i) {
            float a = bf2f(au2[i] & 0xffff), u = bf2f(au2[i] >> 16);
            Ub = a * Ub + u; Ab *= a;
        }
        CA[hc * 132 + w] = Af; CU[hc * 132 + w] = Uf;
        DA[hc * 132 + w] = Ab; DU[hc * 132 + w] = Ub;
    }
    __syncthreads();

    if (tid < 128) {
        float s = 0.f;
#pragma unroll
        for (int k = 0; k < 8; ++k) {
            float Aa = CA[k * 132 + tid], Uu = CU[k * 132 + tid];
            CU[k * 132 + tid] = s;
            s = Aa * s + Uu;
        }
    } else if (tid < 256) {
        int ww = tid - 128;
        float s = 0.f;
#pragma unroll
        for (int k = 7; k >= 0; --k) {
            float Aa = DA[k * 132 + ww], Uu = DU[k * 132 + ww];
            DU[k * 132 + ww] = s;
            s = Aa * s + Uu;
        }
    }
    __syncthreads();

    {
        float sf = CU[hc * 132 + w];
        float sfa[16];
#pragma unroll
        for (int i = 0; i < 16; ++i) {
            float a = bf2f(au2[i] & 0xffff), u = bf2f(au2[i] >> 16);
            sf = a * sf + u; sfa[i] = sf;
        }
        float sb = DU[hc * 132 + w];
#pragma unroll
        for (int i = 15; i >= 0; --i) {
            float a = bf2f(au2[i] & 0xffff), u = bf2f(au2[i] >> 16);
            sb = a * sb + u;
            int hh = h0 + i;
            size_t off = pb + (size_t)hh * W + w;
            float g = bf2f(G_[off]);
            float wsum = Sl[hh * W + (w ^ ((hh & 7) << 2))];
            float v = bf2f(LY[off]) + 0.5f * g * (wsum + sfa[i] + sb);
            LY[off] = f2bf(v / (1.f + __expf(-v)));
        }
    }
}

extern "C" void kernel_launch(void* const* d_in, const int* in_sizes, int n_in,
                              void* d_out, int out_size, void* d_ws, size_t ws_size,
                              hipStream_t stream) {
    const float* x     = (const float*)d_in[0];
    const float* ln_w  = (const float*)d_in[1];
    const float* ln_b  = (const float*)d_in[2];
    const float* dw_w  = (const float*)d_in[3];
    const float* loc_w = (const float*)d_in[4];
    const float* loc_b = (const float*)d_in[5];
    const float* par_w = (const float*)d_in[6];
    const float* par_b = (const float*)d_in[7];
    const float* out_w = (const float*)d_in[8];
    const float* out_b = (const float*)d_in[9];
    float* out = (float*)d_out;
    unsigned short* wsu = (unsigned short*)d_ws;

    // ws (bf16 units): WB(184320) | A | U | G | ZT(->LOC->Y) | DT, each nb*CHW
    const int WBN = 5 * C * K;                 // 184320
    int nb = 8;
    while (nb > 1) {
        size_t need = (size_t)WBN * 2 + (size_t)5 * nb * CHW * 2;
        if (need <= ws_size) break;
        nb >>= 1;
    }

    prepack_kernel<<<(WBN + 255) / 256, 256, 0, stream>>>(par_w, loc_w, out_w, wsu);

    const size_t SCAN_LDS = (size_t)(2 * HW + 4 * 1056) * 4;   // 147,968 B

    for (int b0 = 0; b0 < B; b0 += nb) {
        size_t ge = (size_t)nb * CHW;
        unsigned short* WB = wsu;
        unsigned short* Ab = wsu + WBN;
        unsigned short* Ub = Ab + ge;
        unsigned short* Gb = Ub + ge;
        unsigned short* ZT = Gb + ge;          // z [p][K]; later LOC (bf16 NCHW), then Y
        unsigned short* DT = ZT + ge;
        const float* xg = x + (size_t)b0 * CHW;
        int npg = nb * HW;

        // 1. fused LayerNorm + gates -> ZT, A, U, G  (512-thread blocks, 256 px)
        lngates_kernel<<<npg / 256, 512, 0, stream>>>(
            xg, ln_w, ln_b, WB, par_b, ZT, Ab, Ub, Gb);
        // 2. depthwise 3x3 -> DT [p][K]  (LDS-tiled)
        dw3x3_kernel<<<nb * 128, 256, 0, stream>>>(ZT, dw_w, DT);
        // 3. local conv -> LOC (bf16 NCHW) overwriting ZT (now dead)
        conv_mfma_kernel<1><<<npg / 128, 256, 0, stream>>>(
            DT, nullptr, WB + 3 * C * K, loc_b, nullptr, nullptr, ZT);
        // 4. fused scans + loc add + silu, in place -> Y (= ZT buffer)
        scan_fused_kernel<<<nb * C, 1024, SCAN_LDS, stream>>>(Ab, Ub, Gb, ZT);
        // 5. out conv (reads Y bf16) + bias + residual -> d_out
        conv_mfma_kernel<2><<<npg / 128, 256, 0, stream>>>(
            nullptr, ZT, WB + 4 * C * K, out_b, xg, out + (size_t)b0 * CHW, nullptr);
    }
}